// Round 5
// baseline (727.958 us; speedup 1.0000x reference)
//
#include <hip/hip_runtime.h>
#include <hip/hip_bf16.h>
#include <math.h>

typedef __bf16 bf16_t;
typedef __bf16 bf16x4 __attribute__((ext_vector_type(4)));
typedef __bf16 bf16x8 __attribute__((ext_vector_type(8)));
typedef float f32x4 __attribute__((ext_vector_type(4)));

#define AS1 __attribute__((address_space(1)))
#define AS3 __attribute__((address_space(3)))

__device__ __forceinline__ void gl_lds16(const bf16_t* g, bf16_t* l) {
  __builtin_amdgcn_global_load_lds((const AS1 void*)g, (AS3 void*)l, 16, 0, 0);
}

// ---------- block reductions (256 threads = 4 waves) ----------
__device__ __forceinline__ float block_sum_f(float v) {
  __shared__ float sb[4];
  #pragma unroll
  for (int o = 32; o; o >>= 1) v += __shfl_xor(v, o);
  if ((threadIdx.x & 63) == 0) sb[threadIdx.x >> 6] = v;
  __syncthreads();
  v = sb[0] + sb[1] + sb[2] + sb[3];
  __syncthreads();
  return v;
}
__device__ __forceinline__ float block_max_f(float v) {
  __shared__ float sm[4];
  #pragma unroll
  for (int o = 32; o; o >>= 1) v = fmaxf(v, __shfl_xor(v, o));
  if ((threadIdx.x & 63) == 0) sm[threadIdx.x >> 6] = v;
  __syncthreads();
  v = fmaxf(fmaxf(sm[0], sm[1]), fmaxf(sm[2], sm[3]));
  __syncthreads();
  return v;
}

// ---------- weight absmean (f64 accumulation, two-pass, deterministic) ----------
__global__ __launch_bounds__(256) void wabs_partial(const float* __restrict__ w, int n4,
                                                    double* __restrict__ part) {
  const float4* w4 = (const float4*)w;
  double s = 0.0;
  const int stride = gridDim.x * blockDim.x;
  for (int i = blockIdx.x * blockDim.x + threadIdx.x; i < n4; i += stride) {
    float4 v = w4[i];
    s += (double)fabsf(v.x) + (double)fabsf(v.y) + (double)fabsf(v.z) + (double)fabsf(v.w);
  }
  #pragma unroll
  for (int o = 32; o; o >>= 1) s += __shfl_xor(s, o);
  __shared__ double sd[4];
  if ((threadIdx.x & 63) == 0) sd[threadIdx.x >> 6] = s;
  __syncthreads();
  if (threadIdx.x == 0) part[blockIdx.x] = sd[0] + sd[1] + sd[2] + sd[3];
}

__global__ __launch_bounds__(256) void wabs_final(const double* __restrict__ part, int np,
                                                  double n, float* __restrict__ fwout) {
  double s = 0.0;
  for (int i = threadIdx.x; i < np; i += blockDim.x) s += part[i];
  #pragma unroll
  for (int o = 32; o; o >>= 1) s += __shfl_xor(s, o);
  __shared__ double sd[4];
  if ((threadIdx.x & 63) == 0) sd[threadIdx.x >> 6] = s;
  __syncthreads();
  if (threadIdx.x == 0) {
    double mean = (sd[0] + sd[1] + sd[2] + sd[3]) / n;
    fwout[0] = (float)fmax(mean, 1e-5);
  }
}

// ---------- ternary weight quantization ----------
__global__ __launch_bounds__(256) void quant_w(const float* __restrict__ w,
                                               const float* __restrict__ fw,
                                               bf16_t* __restrict__ wq, int n4) {
  int i = blockIdx.x * blockDim.x + threadIdx.x;
  if (i >= n4) return;
  const float s = 1.0f / fw[0];
  float4 v = ((const float4*)w)[i];
  bf16x4 q;
  q[0] = (bf16_t)fminf(fmaxf(rintf(v.x * s), -1.f), 1.f);
  q[1] = (bf16_t)fminf(fmaxf(rintf(v.y * s), -1.f), 1.f);
  q[2] = (bf16_t)fminf(fmaxf(rintf(v.z * s), -1.f), 1.f);
  q[3] = (bf16_t)fminf(fmaxf(rintf(v.w * s), -1.f), 1.f);
  ((bf16x4*)wq)[i] = q;
}

// ---------- rms_norm + act_quant of x rows (K = 2048) ----------
__global__ __launch_bounds__(256) void rms_quant_x(const float* __restrict__ x,
                                                   bf16_t* __restrict__ xq,
                                                   float* __restrict__ fx, int K) {
  const int row = blockIdx.x, t = threadIdx.x;
  const size_t base = (size_t)row * K;
  float v[8];
  float ss = 0.f;
  #pragma unroll
  for (int j = 0; j < 2; j++) {
    float4 lv = *(const float4*)(x + base + j * 1024 + t * 4);
    v[j*4+0] = lv.x; v[j*4+1] = lv.y; v[j*4+2] = lv.z; v[j*4+3] = lv.w;
  }
  #pragma unroll
  for (int i = 0; i < 8; i++) ss += v[i] * v[i];
  ss = block_sum_f(ss);
  const float r = 1.0f / sqrtf(ss / (float)K + 1e-5f);
  float amax = 0.f;
  #pragma unroll
  for (int i = 0; i < 8; i++) { v[i] *= r; amax = fmaxf(amax, fabsf(v[i])); }
  amax = block_max_f(amax);
  amax = fmaxf(amax, 1e-5f);
  const float scale = 127.0f / amax;
  #pragma unroll
  for (int j = 0; j < 2; j++) {
    bf16x4 q;
    #pragma unroll
    for (int e = 0; e < 4; e++)
      q[e] = (bf16_t)fminf(fmaxf(rintf(v[j*4+e] * scale), -128.f), 127.f);
    *(bf16x4*)(xq + base + j * 1024 + t * 4) = q;
  }
  if (t == 0) fx[row] = amax / 127.0f;
}

// ---------- LayerNorm -> rms_norm -> act_quant, IN-PLACE on bf16 h rows (N = 8192) ----
__global__ __launch_bounds__(256) void ln_rms_quant(bf16_t* h,
                                                    const float* __restrict__ g,
                                                    const float* __restrict__ bb,
                                                    float* __restrict__ fh, int N) {
  const int row = blockIdx.x, t = threadIdx.x;
  const size_t base = (size_t)row * N;
  float v[32];
  float s = 0.f, ss = 0.f;
  #pragma unroll
  for (int j = 0; j < 8; j++) {
    const int col = j * 1024 + t * 4;
    bf16x4 q = *(const bf16x4*)(h + base + col);
    v[j*4+0] = (float)q[0]; v[j*4+1] = (float)q[1];
    v[j*4+2] = (float)q[2]; v[j*4+3] = (float)q[3];
  }
  #pragma unroll
  for (int i = 0; i < 32; i++) { s += v[i]; ss += v[i] * v[i]; }
  s = block_sum_f(s);
  ss = block_sum_f(ss);
  const float mu = s / (float)N;
  const float var = ss / (float)N - mu * mu;
  const float rstd = 1.0f / sqrtf(var + 1e-5f);
  float ss2 = 0.f;
  #pragma unroll
  for (int j = 0; j < 8; j++) {
    const int col = j * 1024 + t * 4;
    float4 gv = *(const float4*)(g + col);
    float4 bv = *(const float4*)(bb + col);
    float y0 = (v[j*4+0] - mu) * rstd * gv.x + bv.x;
    float y1 = (v[j*4+1] - mu) * rstd * gv.y + bv.y;
    float y2 = (v[j*4+2] - mu) * rstd * gv.z + bv.z;
    float y3 = (v[j*4+3] - mu) * rstd * gv.w + bv.w;
    v[j*4+0] = y0; v[j*4+1] = y1; v[j*4+2] = y2; v[j*4+3] = y3;
    ss2 += y0*y0 + y1*y1 + y2*y2 + y3*y3;
  }
  ss2 = block_sum_f(ss2);
  const float r2 = 1.0f / sqrtf(ss2 / (float)N + 1e-5f);
  float amax = 0.f;
  #pragma unroll
  for (int i = 0; i < 32; i++) { v[i] *= r2; amax = fmaxf(amax, fabsf(v[i])); }
  amax = block_max_f(amax);
  amax = fmaxf(amax, 1e-5f);
  const float scale = 127.0f / amax;
  #pragma unroll
  for (int j = 0; j < 8; j++) {
    const int col = j * 1024 + t * 4;
    bf16x4 q;
    #pragma unroll
    for (int e = 0; e < 4; e++)
      q[e] = (bf16_t)fminf(fmaxf(rintf(v[j*4+e] * scale), -128.f), 127.f);
    *(bf16x4*)(h + base + col) = q;
  }
  if (t == 0) fh[row] = amax / 127.0f;
}

// ================= 256x256 GEMM, overlap schedule (B stored [N][K]) =================
// 8 waves (2Mx4N). BK=64. LDS subtile = [16 rows][2 kk][16][32] (1KB elems);
// slot swizzle uses row bits 1,2: content(r, slot) = global slot (slot ^ sw(r)),
// sw(r) = 2*bit2(r) + bit1(r)  -> consecutive-8-lane b128 reads hit 8 distinct
// 4-bank slots (conflict-free at 128B/cyc granularity).
// Per K-tile: issue all reads, 4 MFMA quadrants back-to-back (compiler inserts
// counted lgkm waits), ONE barrier, stage t+2 (vmcnt-only), counted vmcnt(8)
// guard for t+1, second barrier. 2 barriers/tile; LDS reads overlap MFMA.
template<int EPI, bool STORE_BF16>
__global__ __launch_bounds__(512, 2) void gemm256(const bf16_t* __restrict__ A,
                                                  const bf16_t* __restrict__ B,
                                                  const float* __restrict__ rowf,
                                                  const float* __restrict__ wf,
                                                  const float* __restrict__ bias,
                                                  float* __restrict__ Cf,
                                                  bf16_t* __restrict__ Cb,
                                                  int M, int N, int K) {
  __shared__ bf16_t smem[65536];   // A[2][16384] then B[2][16384] elements

  const int ntile = N >> 8;
  const int cpx = gridDim.x >> 3;
  const int bid = blockIdx.x;
  const int wg = (bid & 7) * cpx + (bid >> 3);    // XCD-bijective swizzle
  const int bm = wg / ntile, bn = wg % ntile;
  const int tm = bm << 8, tn = bn << 8;

  const int tid = threadIdx.x;
  const int w = tid >> 6, lane = tid & 63;
  const int wm = w >> 2, wn = w & 3;              // 2 x 4 wave grid
  const int ln15 = lane & 15;

  // ---- staging: wave w owns rowblk w (lo) / 8+w (hi); pre-swizzled source col.
  // row = lane>>2 (0..15), slot = lane&3; srcCol = 8*(slot ^ (2*bit2(row)+bit1(row)))
  const int srcRow = lane >> 2;
  const int srcCol = ((lane & 3) * 8) ^ ((lane & 16) ? 16 : 0) ^ ((lane & 8) ? 8 : 0);
  const size_t KS = (size_t)K;
  const bf16_t* pAb = A + (size_t)(tm + w * 16 + srcRow) * KS + srcCol;
  const bf16_t* pBb = B + (size_t)(tn + w * 16 + srcRow) * KS + srcCol;
  const size_t hiO = (size_t)128 * KS;            // +128 rows for the hi half
  const int dA = w * 1024;                        // dest elem offset of wave's subtile

  // ---- fragment read offset (row = ln15, want global slot hi = lane>>4):
  // LDS slot = hi ^ sw(ln15), sw = 2*bit2 + bit1
  const int kcr = ((lane >> 4) * 8) ^ ((ln15 & 4) ? 16 : 0) ^ ((ln15 & 2) ? 8 : 0);
  const int foff = ln15 * 32 + kcr;

  f32x4 acc[8][4] = {};
  const int NT = K >> 6;

#define SB __builtin_amdgcn_sched_barrier(0)
#define BAR { SB; __builtin_amdgcn_s_barrier(); SB; }
#define ST_ALO(bb, kt) { const bf16_t* p = pAb + (size_t)(kt) * 64;        \
    gl_lds16(p,      smem + (bb) * 16384 + dA);                            \
    gl_lds16(p + 32, smem + (bb) * 16384 + dA + 512); }
#define ST_AHI(bb, kt) { const bf16_t* p = pAb + hiO + (size_t)(kt) * 64;  \
    gl_lds16(p,      smem + (bb) * 16384 + 8192 + dA);                     \
    gl_lds16(p + 32, smem + (bb) * 16384 + 8192 + dA + 512); }
#define ST_BLO(bb, kt) { const bf16_t* p = pBb + (size_t)(kt) * 64;        \
    gl_lds16(p,      smem + 32768 + (bb) * 16384 + dA);                    \
    gl_lds16(p + 32, smem + 32768 + (bb) * 16384 + dA + 512); }
#define ST_BHI(bb, kt) { const bf16_t* p = pBb + hiO + (size_t)(kt) * 64;  \
    gl_lds16(p,      smem + 32768 + (bb) * 16384 + 8192 + dA);             \
    gl_lds16(p + 32, smem + 32768 + (bb) * 16384 + 8192 + dA + 512); }
#define MM(AF, BF, MB, NB)                                                 \
  _Pragma("unroll") for (int m4 = 0; m4 < 4; m4++)                         \
    _Pragma("unroll") for (int n2 = 0; n2 < 2; n2++)                       \
      _Pragma("unroll") for (int kk = 0; kk < 2; kk++)                     \
        acc[(MB)+m4][(NB)+n2] = __builtin_amdgcn_mfma_f32_16x16x32_bf16(   \
            AF[m4][kk], BF[n2][kk], acc[(MB)+m4][(NB)+n2], 0, 0, 0);

  // ---- prologue: stage tile0 + tile1 fully; wait tile0; barrier ----
  ST_ALO(0, 0); ST_AHI(0, 0); ST_BLO(0, 0); ST_BHI(0, 0);
  ST_ALO(1, 1); ST_AHI(1, 1); ST_BLO(1, 1); ST_BHI(1, 1);
  asm volatile("s_waitcnt vmcnt(8)" ::: "memory");
  BAR;

  for (int t = 0; t < NT; ++t) {
    const int b = t & 1;
    const bf16_t* sA = smem + b * 16384;
    const bf16_t* sB = smem + 32768 + b * 16384;
    bf16x8 afL[4][2], afH[4][2], bL[2][2], bH[2][2];
    // issue A-lo + B-lo + A-hi reads (20 b128); compiler inserts counted lgkm waits
    #pragma unroll
    for (int m4 = 0; m4 < 4; m4++)
      #pragma unroll
      for (int kk = 0; kk < 2; kk++)
        afL[m4][kk] = *(const bf16x8*)(sA + (wm * 4 + m4) * 1024 + kk * 512 + foff);
    #pragma unroll
    for (int n2 = 0; n2 < 2; n2++)
      #pragma unroll
      for (int kk = 0; kk < 2; kk++)
        bL[n2][kk] = *(const bf16x8*)(sB + (wn * 2 + n2) * 1024 + kk * 512 + foff);
    #pragma unroll
    for (int m4 = 0; m4 < 4; m4++)
      #pragma unroll
      for (int kk = 0; kk < 2; kk++)
        afH[m4][kk] = *(const bf16x8*)(sA + 8192 + (wm * 4 + m4) * 1024 + kk * 512 + foff);
    __builtin_amdgcn_s_setprio(1);
    MM(afL, bL, 0, 0);           // q0
    MM(afH, bL, 4, 0);           // q1 (bL dies)
    __builtin_amdgcn_s_setprio(0);
    // issue B-hi reads (4 b128)
    #pragma unroll
    for (int n2 = 0; n2 < 2; n2++)
      #pragma unroll
      for (int kk = 0; kk < 2; kk++)
        bH[n2][kk] = *(const bf16x8*)(sB + 8192 + (wn * 2 + n2) * 1024 + kk * 512 + foff);
    __builtin_amdgcn_s_setprio(1);
    MM(afH, bH, 4, 2);           // q2 (afH dies)
    MM(afL, bH, 0, 2);           // q3
    __builtin_amdgcn_s_setprio(0);
    BAR;                         // all waves done reading buffer b
    if (t + 2 < NT) {
      ST_ALO(b, t + 2); ST_AHI(b, t + 2); ST_BLO(b, t + 2); ST_BHI(b, t + 2);
      asm volatile("s_waitcnt vmcnt(8)" ::: "memory");   // tile t+1 landed
    } else if (t + 1 < NT) {
      asm volatile("s_waitcnt vmcnt(0)" ::: "memory");
    }
    BAR;                         // all waves verified t+1 landed
  }
#undef ST_ALO
#undef ST_AHI
#undef ST_BLO
#undef ST_BHI
#undef MM

  // ---- epilogue: dequant + bias (+ SiLU+GELU) ----
  const float fwv = wf[0];
  const int rq = (lane >> 4) << 2;
  float rsc[8][4];
  #pragma unroll
  for (int m = 0; m < 8; m++)
    #pragma unroll
    for (int r = 0; r < 4; r++)
      rsc[m][r] = rowf[tm + (m >> 2) * 128 + wm * 64 + (m & 3) * 16 + rq + r] * fwv;

  #pragma unroll
  for (int m = 0; m < 8; m++) {
    #pragma unroll
    for (int n = 0; n < 4; n++) {
      const int col = tn + (n >> 1) * 128 + wn * 32 + (n & 1) * 16 + ln15;
      const float bv = bias[col];
      #pragma unroll
      for (int r = 0; r < 4; r++) {
        const int row = tm + (m >> 2) * 128 + wm * 64 + (m & 3) * 16 + rq + r;
        float val = acc[m][n][r] * rsc[m][r] + bv;
        if (EPI == 1) {
          float sl = val / (1.0f + expf(-val));                       // SiLU
          val = 0.5f * sl * (1.0f + erff(sl * 0.70710678118654752f)); // exact GELU
        }
        if (STORE_BF16) Cb[(size_t)row * N + col] = (bf16_t)val;
        else            Cf[(size_t)row * N + col] = val;
      }
    }
  }
}

extern "C" void kernel_launch(void* const* d_in, const int* in_sizes, int n_in,
                              void* d_out, int out_size, void* d_ws, size_t ws_size,
                              hipStream_t stream) {
  const float* x   = (const float*)d_in[0];
  const float* w1  = (const float*)d_in[1];
  const float* b1  = (const float*)d_in[2];
  const float* lng = (const float*)d_in[3];
  const float* lnb = (const float*)d_in[4];
  const float* w2  = (const float*)d_in[5];
  const float* b2  = (const float*)d_in[6];
  float* out = (float*)d_out;

  const int inner = in_sizes[2];           // 8192
  const int d     = in_sizes[1] / inner;   // 2048
  const int M     = in_sizes[0] / d;       // 8192

  char* ws = (char*)d_ws;
  size_t off = 0;
  double* part = (double*)(ws + off); off += 1024 * 8;
  float*  fw   = (float*)(ws + off);  off += 256;
  float*  fx   = (float*)(ws + off);  off += (size_t)M * 4;
  float*  fh   = (float*)(ws + off);  off += (size_t)M * 4;
  bf16_t* w1q  = (bf16_t*)(ws + off); off += (size_t)inner * d * 2;
  bf16_t* w2q  = (bf16_t*)(ws + off); off += (size_t)inner * d * 2;

  int MC = M;  // multiple of 256
  while (MC > 256 && off + (size_t)MC * (size_t)(d + inner) * 2 > ws_size) MC >>= 1;
  bf16_t* xq = (bf16_t*)(ws + off); off += (size_t)MC * d * 2;
  bf16_t* hq = (bf16_t*)(ws + off);

  const int nw = inner * d;
  const int n4 = nw / 4;

  wabs_partial<<<1024, 256, 0, stream>>>(w1, n4, part);
  wabs_final<<<1, 256, 0, stream>>>(part, 1024, (double)nw, fw + 0);
  wabs_partial<<<1024, 256, 0, stream>>>(w2, n4, part);
  wabs_final<<<1, 256, 0, stream>>>(part, 1024, (double)nw, fw + 1);
  quant_w<<<n4 / 256, 256, 0, stream>>>(w1, fw + 0, w1q, n4);
  quant_w<<<n4 / 256, 256, 0, stream>>>(w2, fw + 1, w2q, n4);

  for (int mc = 0; mc < M; mc += MC) {
    rms_quant_x<<<MC, 256, 0, stream>>>(x + (size_t)mc * d, xq, fx, d);

    const int g1 = (MC / 256) * (inner / 256);
    gemm256<1, true><<<g1, 512, 0, stream>>>(xq, w1q, fx, fw + 0, b1,
                                             nullptr, hq, MC, inner, d);

    ln_rms_quant<<<MC, 256, 0, stream>>>(hq, lng, lnb, fh, inner);

    const int g2 = (MC / 256) * (d / 256);
    gemm256<0, false><<<g2, 512, 0, stream>>>(hq, w2q, fh, fw + 1, b2,
                                              out + (size_t)mc * d, nullptr, MC, d, inner);
  }
}

// Round 6
// 489.254 us; speedup vs baseline: 1.4879x; 1.4879x over previous
//
#include <hip/hip_runtime.h>
#include <hip/hip_bf16.h>
#include <math.h>

typedef __bf16 bf16_t;
typedef __bf16 bf16x4 __attribute__((ext_vector_type(4)));
typedef int i32x4 __attribute__((ext_vector_type(4)));

#define AS1 __attribute__((address_space(1)))
#define AS3 __attribute__((address_space(3)))

__device__ __forceinline__ void gl_lds16(const char* g, char* l) {
  __builtin_amdgcn_global_load_lds((const AS1 void*)g, (AS3 void*)l, 16, 0, 0);
}

__device__ __forceinline__ unsigned pack4i(float a, float b, float c, float d) {
  return ((unsigned)(unsigned char)(int)a) | ((unsigned)(unsigned char)(int)b << 8) |
         ((unsigned)(unsigned char)(int)c << 16) | ((unsigned)(unsigned char)(int)d << 24);
}

// ---------- block reductions (256 threads = 4 waves) ----------
__device__ __forceinline__ float block_sum_f(float v) {
  __shared__ float sb[4];
  #pragma unroll
  for (int o = 32; o; o >>= 1) v += __shfl_xor(v, o);
  if ((threadIdx.x & 63) == 0) sb[threadIdx.x >> 6] = v;
  __syncthreads();
  v = sb[0] + sb[1] + sb[2] + sb[3];
  __syncthreads();
  return v;
}
__device__ __forceinline__ float block_max_f(float v) {
  __shared__ float sm[4];
  #pragma unroll
  for (int o = 32; o; o >>= 1) v = fmaxf(v, __shfl_xor(v, o));
  if ((threadIdx.x & 63) == 0) sm[threadIdx.x >> 6] = v;
  __syncthreads();
  v = fmaxf(fmaxf(sm[0], sm[1]), fmaxf(sm[2], sm[3]));
  __syncthreads();
  return v;
}

// ---------- weight absmean (f64 accumulation, two-pass, deterministic) ----------
__global__ __launch_bounds__(256) void wabs_partial(const float* __restrict__ w, int n4,
                                                    double* __restrict__ part) {
  const float4* w4 = (const float4*)w;
  double s = 0.0;
  const int stride = gridDim.x * blockDim.x;
  for (int i = blockIdx.x * blockDim.x + threadIdx.x; i < n4; i += stride) {
    float4 v = w4[i];
    s += (double)fabsf(v.x) + (double)fabsf(v.y) + (double)fabsf(v.z) + (double)fabsf(v.w);
  }
  #pragma unroll
  for (int o = 32; o; o >>= 1) s += __shfl_xor(s, o);
  __shared__ double sd[4];
  if ((threadIdx.x & 63) == 0) sd[threadIdx.x >> 6] = s;
  __syncthreads();
  if (threadIdx.x == 0) part[blockIdx.x] = sd[0] + sd[1] + sd[2] + sd[3];
}

__global__ __launch_bounds__(256) void wabs_final(const double* __restrict__ part, int np,
                                                  double n, float* __restrict__ fwout) {
  double s = 0.0;
  for (int i = threadIdx.x; i < np; i += blockDim.x) s += part[i];
  #pragma unroll
  for (int o = 32; o; o >>= 1) s += __shfl_xor(s, o);
  __shared__ double sd[4];
  if ((threadIdx.x & 63) == 0) sd[threadIdx.x >> 6] = s;
  __syncthreads();
  if (threadIdx.x == 0) {
    double mean = (sd[0] + sd[1] + sd[2] + sd[3]) / n;
    fwout[0] = (float)fmax(mean, 1e-5);
  }
}

// ---------- ternary weight quantization -> int8 {-1,0,1} ----------
__global__ __launch_bounds__(256) void quant_w(const float* __restrict__ w,
                                               const float* __restrict__ fw,
                                               char* __restrict__ wq, int n4) {
  int i = blockIdx.x * blockDim.x + threadIdx.x;
  if (i >= n4) return;
  const float s = 1.0f / fw[0];
  float4 v = ((const float4*)w)[i];
  ((unsigned*)wq)[i] = pack4i(fminf(fmaxf(rintf(v.x * s), -1.f), 1.f),
                              fminf(fmaxf(rintf(v.y * s), -1.f), 1.f),
                              fminf(fmaxf(rintf(v.z * s), -1.f), 1.f),
                              fminf(fmaxf(rintf(v.w * s), -1.f), 1.f));
}

// ---------- rms_norm + act_quant of x rows (K = 2048) -> int8 + scale ----------
__global__ __launch_bounds__(256) void rms_quant_x(const float* __restrict__ x,
                                                   char* __restrict__ xq,
                                                   float* __restrict__ fx, int K) {
  const int row = blockIdx.x, t = threadIdx.x;
  const size_t base = (size_t)row * K;
  float v[8];
  float ss = 0.f;
  #pragma unroll
  for (int j = 0; j < 2; j++) {
    float4 lv = *(const float4*)(x + base + j * 1024 + t * 4);
    v[j*4+0] = lv.x; v[j*4+1] = lv.y; v[j*4+2] = lv.z; v[j*4+3] = lv.w;
  }
  #pragma unroll
  for (int i = 0; i < 8; i++) ss += v[i] * v[i];
  ss = block_sum_f(ss);
  const float r = 1.0f / sqrtf(ss / (float)K + 1e-5f);
  float amax = 0.f;
  #pragma unroll
  for (int i = 0; i < 8; i++) { v[i] *= r; amax = fmaxf(amax, fabsf(v[i])); }
  amax = block_max_f(amax);
  amax = fmaxf(amax, 1e-5f);
  const float scale = 127.0f / amax;
  #pragma unroll
  for (int j = 0; j < 2; j++) {
    float q[4];
    #pragma unroll
    for (int e = 0; e < 4; e++)
      q[e] = fminf(fmaxf(rintf(v[j*4+e] * scale), -128.f), 127.f);
    *(unsigned*)(xq + base + j * 1024 + t * 4) = pack4i(q[0], q[1], q[2], q[3]);
  }
  if (t == 0) fx[row] = amax / 127.0f;
}

// ---------- LayerNorm -> rms_norm -> act_quant: bf16 h rows -> int8 hq (N = 8192) ----
__global__ __launch_bounds__(256) void ln_rms_quant(const bf16_t* __restrict__ h,
                                                    char* __restrict__ hq,
                                                    const float* __restrict__ g,
                                                    const float* __restrict__ bb,
                                                    float* __restrict__ fh, int N) {
  const int row = blockIdx.x, t = threadIdx.x;
  const size_t base = (size_t)row * N;
  float v[32];
  float s = 0.f, ss = 0.f;
  #pragma unroll
  for (int j = 0; j < 8; j++) {
    const int col = j * 1024 + t * 4;
    bf16x4 q = *(const bf16x4*)(h + base + col);
    v[j*4+0] = (float)q[0]; v[j*4+1] = (float)q[1];
    v[j*4+2] = (float)q[2]; v[j*4+3] = (float)q[3];
  }
  #pragma unroll
  for (int i = 0; i < 32; i++) { s += v[i]; ss += v[i] * v[i]; }
  s = block_sum_f(s);
  ss = block_sum_f(ss);
  const float mu = s / (float)N;
  const float var = ss / (float)N - mu * mu;
  const float rstd = 1.0f / sqrtf(var + 1e-5f);
  float ss2 = 0.f;
  #pragma unroll
  for (int j = 0; j < 8; j++) {
    const int col = j * 1024 + t * 4;
    float4 gv = *(const float4*)(g + col);
    float4 bv = *(const float4*)(bb + col);
    float y0 = (v[j*4+0] - mu) * rstd * gv.x + bv.x;
    float y1 = (v[j*4+1] - mu) * rstd * gv.y + bv.y;
    float y2 = (v[j*4+2] - mu) * rstd * gv.z + bv.z;
    float y3 = (v[j*4+3] - mu) * rstd * gv.w + bv.w;
    v[j*4+0] = y0; v[j*4+1] = y1; v[j*4+2] = y2; v[j*4+3] = y3;
    ss2 += y0*y0 + y1*y1 + y2*y2 + y3*y3;
  }
  ss2 = block_sum_f(ss2);
  const float r2 = 1.0f / sqrtf(ss2 / (float)N + 1e-5f);
  float amax = 0.f;
  #pragma unroll
  for (int i = 0; i < 32; i++) { v[i] *= r2; amax = fmaxf(amax, fabsf(v[i])); }
  amax = block_max_f(amax);
  amax = fmaxf(amax, 1e-5f);
  const float scale = 127.0f / amax;
  #pragma unroll
  for (int j = 0; j < 8; j++) {
    const int col = j * 1024 + t * 4;
    float q[4];
    #pragma unroll
    for (int e = 0; e < 4; e++)
      q[e] = fminf(fmaxf(rintf(v[j*4+e] * scale), -128.f), 127.f);
    *(unsigned*)(hq + base + col) = pack4i(q[0], q[1], q[2], q[3]);
  }
  if (t == 0) fh[row] = amax / 127.0f;
}

// ================= 256x256 i8 GEMM (B stored [N][K], both int8) =================
// 8 waves (2Mx4N). BK=64 = one mfma_i32_16x16x64_i8 per frag-pair (K=64/instr).
// LDS per buffer: A = 16 rowblk subtiles [16 rows][4 slots x 16B] (1KB each, 16KB),
// B same; double-buffered = 64 KB total. Slot swizzle: phys_slot = slot ^ ((row>>1)&3)
// -> consecutive-8-lane b128 reads hit 8 distinct 16B slots (conflict-free).
// Per K-tile: 12 ds_read_b128 + 32 MFMA (compiler-counted lgkm), ONE barrier,
// stage tile t+2 (4 gl_lds16/wave), counted vmcnt(4) guard for t+1, second barrier.
template<int EPI, bool STORE_BF16>
__global__ __launch_bounds__(512, 2) void gemm256(const char* __restrict__ A,
                                                  const char* __restrict__ B,
                                                  const float* __restrict__ rowf,
                                                  const float* __restrict__ wf,
                                                  const float* __restrict__ bias,
                                                  float* __restrict__ Cf,
                                                  bf16_t* __restrict__ Cb,
                                                  int M, int N, int K) {
  __shared__ char smem[65536];   // A[2][16384] then B[2][16384] bytes

  const int ntile = N >> 8;
  const int cpx = gridDim.x >> 3;
  const int bid = blockIdx.x;
  const int wg = (bid & 7) * cpx + (bid >> 3);    // XCD-bijective swizzle
  const int bm = wg / ntile, bn = wg % ntile;
  const int tm = bm << 8, tn = bn << 8;

  const int tid = threadIdx.x;
  const int w = tid >> 6, lane = tid & 63;
  const int wm = w >> 2, wn = w & 3;              // 2 x 4 wave grid
  const int ln15 = lane & 15;

  // ---- staging: wave w stages rowblk w (lo) and 8+w (hi) of each operand.
  // lane -> row = lane>>2 (0..15), slot = lane&3; pre-swizzled source column.
  const int srcRow = lane >> 2;
  const int srcCol = (((lane & 3) ^ ((lane >> 3) & 3)) << 4);
  const size_t KS = (size_t)K;
  const char* pAb = A + (size_t)(tm + w * 16 + srcRow) * KS + srcCol;
  const char* pBb = B + (size_t)(tn + w * 16 + srcRow) * KS + srcCol;
  const size_t hiO = (size_t)128 * KS;            // +128 rows for the hi half
  const int dA = w * 1024;                        // byte offset of wave's subtile

  // ---- fragment read offset: row=ln15, global slot g=lane>>4,
  // phys slot = g ^ ((ln15>>1)&3); 16B aligned.
  const int foff = ln15 * 64 + ((((lane >> 4) ^ ((ln15 >> 1) & 3))) << 4);

  i32x4 acc[8][4] = {};
  const int NT = K >> 6;

#define SB __builtin_amdgcn_sched_barrier(0)
#define BAR { SB; __builtin_amdgcn_s_barrier(); SB; }
#define ST_ALO(bb, kt) gl_lds16(pAb + (size_t)(kt) * 64, smem + (bb) * 16384 + dA);
#define ST_AHI(bb, kt) gl_lds16(pAb + hiO + (size_t)(kt) * 64, smem + (bb) * 16384 + 8192 + dA);
#define ST_BLO(bb, kt) gl_lds16(pBb + (size_t)(kt) * 64, smem + 32768 + (bb) * 16384 + dA);
#define ST_BHI(bb, kt) gl_lds16(pBb + hiO + (size_t)(kt) * 64, smem + 32768 + (bb) * 16384 + 8192 + dA);
#define MM(AF, BF, MB, NB)                                                   \
  _Pragma("unroll") for (int m4 = 0; m4 < 4; m4++)                           \
    _Pragma("unroll") for (int n2 = 0; n2 < 2; n2++)                         \
      acc[(MB)+m4][(NB)+n2] = __builtin_amdgcn_mfma_i32_16x16x64_i8(         \
          AF[m4], BF[n2], acc[(MB)+m4][(NB)+n2], 0, 0, 0);

  // ---- prologue: stage tile0 + tile1; wait tile0; barrier ----
  ST_ALO(0, 0); ST_AHI(0, 0); ST_BLO(0, 0); ST_BHI(0, 0);
  ST_ALO(1, 1); ST_AHI(1, 1); ST_BLO(1, 1); ST_BHI(1, 1);
  asm volatile("s_waitcnt vmcnt(4)" ::: "memory");
  BAR;

  for (int t = 0; t < NT; ++t) {
    const int b = t & 1;
    const char* sA = smem + b * 16384;
    const char* sB = smem + 32768 + b * 16384;
    i32x4 afL[4], afH[4], bL[2], bH[2];
    #pragma unroll
    for (int m4 = 0; m4 < 4; m4++)
      afL[m4] = *(const i32x4*)(sA + (wm * 4 + m4) * 1024 + foff);
    #pragma unroll
    for (int n2 = 0; n2 < 2; n2++)
      bL[n2] = *(const i32x4*)(sB + (wn * 2 + n2) * 1024 + foff);
    #pragma unroll
    for (int m4 = 0; m4 < 4; m4++)
      afH[m4] = *(const i32x4*)(sA + 8192 + (wm * 4 + m4) * 1024 + foff);
    #pragma unroll
    for (int n2 = 0; n2 < 2; n2++)
      bH[n2] = *(const i32x4*)(sB + 8192 + (wn * 2 + n2) * 1024 + foff);
    __builtin_amdgcn_s_setprio(1);
    MM(afL, bL, 0, 0);
    MM(afH, bL, 4, 0);
    MM(afH, bH, 4, 2);
    MM(afL, bH, 0, 2);
    __builtin_amdgcn_s_setprio(0);
    BAR;                         // all waves done reading buffer b
    if (t + 2 < NT) {
      ST_ALO(b, t + 2); ST_AHI(b, t + 2); ST_BLO(b, t + 2); ST_BHI(b, t + 2);
      asm volatile("s_waitcnt vmcnt(4)" ::: "memory");   // tile t+1 landed
    } else if (t + 1 < NT) {
      asm volatile("s_waitcnt vmcnt(0)" ::: "memory");
    }
    BAR;                         // all waves verified t+1 landed
  }
#undef ST_ALO
#undef ST_AHI
#undef ST_BLO
#undef ST_BHI
#undef MM

  // ---- epilogue: dequant + bias (+ SiLU+GELU) ----
  const float fwv = wf[0];
  const int rq = (lane >> 4) << 2;
  float rsc[8][4];
  #pragma unroll
  for (int m = 0; m < 8; m++)
    #pragma unroll
    for (int r = 0; r < 4; r++)
      rsc[m][r] = rowf[tm + (m >> 2) * 128 + wm * 64 + (m & 3) * 16 + rq + r] * fwv;

  #pragma unroll
  for (int m = 0; m < 8; m++) {
    #pragma unroll
    for (int n = 0; n < 4; n++) {
      const int col = tn + (n >> 1) * 128 + wn * 32 + (n & 1) * 16 + ln15;
      const float bv = bias[col];
      #pragma unroll
      for (int r = 0; r < 4; r++) {
        const int row = tm + (m >> 2) * 128 + wm * 64 + (m & 3) * 16 + rq + r;
        float val = (float)acc[m][n][r] * rsc[m][r] + bv;
        if (EPI == 1) {
          float sl = val / (1.0f + expf(-val));                       // SiLU
          val = 0.5f * sl * (1.0f + erff(sl * 0.70710678118654752f)); // exact GELU
        }
        if (STORE_BF16) Cb[(size_t)row * N + col] = (bf16_t)val;
        else            Cf[(size_t)row * N + col] = val;
      }
    }
  }
}

extern "C" void kernel_launch(void* const* d_in, const int* in_sizes, int n_in,
                              void* d_out, int out_size, void* d_ws, size_t ws_size,
                              hipStream_t stream) {
  const float* x   = (const float*)d_in[0];
  const float* w1  = (const float*)d_in[1];
  const float* b1  = (const float*)d_in[2];
  const float* lng = (const float*)d_in[3];
  const float* lnb = (const float*)d_in[4];
  const float* w2  = (const float*)d_in[5];
  const float* b2  = (const float*)d_in[6];
  float* out = (float*)d_out;

  const int inner = in_sizes[2];           // 8192
  const int d     = in_sizes[1] / inner;   // 2048
  const int M     = in_sizes[0] / d;       // 8192

  char* ws = (char*)d_ws;
  size_t off = 0;
  double* part = (double*)(ws + off); off += 1024 * 8;
  float*  fw   = (float*)(ws + off);  off += 256;
  float*  fx   = (float*)(ws + off);  off += (size_t)M * 4;
  float*  fh   = (float*)(ws + off);  off += (size_t)M * 4;
  char*   w1q  = ws + off;            off += (size_t)inner * d;
  char*   w2q  = ws + off;            off += (size_t)inner * d;

  // chunk: xq (MC*d i8) + h (MC*inner bf16) + hq (MC*inner i8)
  int MC = M;  // multiple of 256
  while (MC > 256 && off + (size_t)MC * ((size_t)d + 3 * (size_t)inner) > ws_size) MC >>= 1;
  char*   xq = ws + off;              off += (size_t)MC * d;
  bf16_t* h  = (bf16_t*)(ws + off);   off += (size_t)MC * inner * 2;
  char*   hq = ws + off;

  const int nw = inner * d;
  const int n4 = nw / 4;

  wabs_partial<<<1024, 256, 0, stream>>>(w1, n4, part);
  wabs_final<<<1, 256, 0, stream>>>(part, 1024, (double)nw, fw + 0);
  wabs_partial<<<1024, 256, 0, stream>>>(w2, n4, part);
  wabs_final<<<1, 256, 0, stream>>>(part, 1024, (double)nw, fw + 1);
  quant_w<<<n4 / 256, 256, 0, stream>>>(w1, fw + 0, w1q, n4);
  quant_w<<<n4 / 256, 256, 0, stream>>>(w2, fw + 1, w2q, n4);

  for (int mc = 0; mc < M; mc += MC) {
    rms_quant_x<<<MC, 256, 0, stream>>>(x + (size_t)mc * d, xq, fx, d);

    const int g1 = (MC / 256) * (inner / 256);
    gemm256<1, true><<<g1, 512, 0, stream>>>(xq, w1q, fx, fw + 0, b1,
                                             nullptr, h, MC, inner, d);

    ln_rms_quant<<<MC, 256, 0, stream>>>(h, hq, lng, lnb, fh, inner);

    const int g2 = (MC / 256) * (d / 256);
    gemm256<0, false><<<g2, 512, 0, stream>>>(hq, w2q, fh, fw + 1, b2,
                                              out + (size_t)mc * d, nullptr, MC, d, inner);
  }
}

// Round 7
// 468.002 us; speedup vs baseline: 1.5555x; 1.0454x over previous
//
#include <hip/hip_runtime.h>
#include <hip/hip_bf16.h>
#include <math.h>

typedef __bf16 bf16_t;
typedef __bf16 bf16x4 __attribute__((ext_vector_type(4)));
typedef int i32x4 __attribute__((ext_vector_type(4)));

#define AS1 __attribute__((address_space(1)))
#define AS3 __attribute__((address_space(3)))

__device__ __forceinline__ void gl_lds16(const char* g, char* l) {
  __builtin_amdgcn_global_load_lds((const AS1 void*)g, (AS3 void*)l, 16, 0, 0);
}

__device__ __forceinline__ unsigned pack4i(float a, float b, float c, float d) {
  return ((unsigned)(unsigned char)(int)a) | ((unsigned)(unsigned char)(int)b << 8) |
         ((unsigned)(unsigned char)(int)c << 16) | ((unsigned)(unsigned char)(int)d << 24);
}

// ---------- block reductions (256 threads = 4 waves) ----------
__device__ __forceinline__ float block_sum_f(float v) {
  __shared__ float sb[4];
  #pragma unroll
  for (int o = 32; o; o >>= 1) v += __shfl_xor(v, o);
  if ((threadIdx.x & 63) == 0) sb[threadIdx.x >> 6] = v;
  __syncthreads();
  v = sb[0] + sb[1] + sb[2] + sb[3];
  __syncthreads();
  return v;
}
__device__ __forceinline__ float block_max_f(float v) {
  __shared__ float sm[4];
  #pragma unroll
  for (int o = 32; o; o >>= 1) v = fmaxf(v, __shfl_xor(v, o));
  if ((threadIdx.x & 63) == 0) sm[threadIdx.x >> 6] = v;
  __syncthreads();
  v = fmaxf(fmaxf(sm[0], sm[1]), fmaxf(sm[2], sm[3]));
  __syncthreads();
  return v;
}

// ---------- weight absmean (f64 accumulation, two-pass, deterministic) ----------
__global__ __launch_bounds__(256) void wabs_partial(const float* __restrict__ w, int n4,
                                                    double* __restrict__ part) {
  const float4* w4 = (const float4*)w;
  double s = 0.0;
  const int stride = gridDim.x * blockDim.x;
  for (int i = blockIdx.x * blockDim.x + threadIdx.x; i < n4; i += stride) {
    float4 v = w4[i];
    s += (double)fabsf(v.x) + (double)fabsf(v.y) + (double)fabsf(v.z) + (double)fabsf(v.w);
  }
  #pragma unroll
  for (int o = 32; o; o >>= 1) s += __shfl_xor(s, o);
  __shared__ double sd[4];
  if ((threadIdx.x & 63) == 0) sd[threadIdx.x >> 6] = s;
  __syncthreads();
  if (threadIdx.x == 0) part[blockIdx.x] = sd[0] + sd[1] + sd[2] + sd[3];
}

__global__ __launch_bounds__(256) void wabs_final(const double* __restrict__ part, int np,
                                                  double n, float* __restrict__ fwout) {
  double s = 0.0;
  for (int i = threadIdx.x; i < np; i += blockDim.x) s += part[i];
  #pragma unroll
  for (int o = 32; o; o >>= 1) s += __shfl_xor(s, o);
  __shared__ double sd[4];
  if ((threadIdx.x & 63) == 0) sd[threadIdx.x >> 6] = s;
  __syncthreads();
  if (threadIdx.x == 0) {
    double mean = (sd[0] + sd[1] + sd[2] + sd[3]) / n;
    fwout[0] = (float)fmax(mean, 1e-5);
  }
}

// ---------- ternary weight quantization -> int8 {-1,0,1} ----------
__global__ __launch_bounds__(256) void quant_w(const float* __restrict__ w,
                                               const float* __restrict__ fw,
                                               char* __restrict__ wq, int n4) {
  int i = blockIdx.x * blockDim.x + threadIdx.x;
  if (i >= n4) return;
  const float s = 1.0f / fw[0];
  float4 v = ((const float4*)w)[i];
  ((unsigned*)wq)[i] = pack4i(fminf(fmaxf(rintf(v.x * s), -1.f), 1.f),
                              fminf(fmaxf(rintf(v.y * s), -1.f), 1.f),
                              fminf(fmaxf(rintf(v.z * s), -1.f), 1.f),
                              fminf(fmaxf(rintf(v.w * s), -1.f), 1.f));
}

// ---------- rms_norm + act_quant of x rows (K = 2048) -> int8 + scale ----------
__global__ __launch_bounds__(256) void rms_quant_x(const float* __restrict__ x,
                                                   char* __restrict__ xq,
                                                   float* __restrict__ fx, int K) {
  const int row = blockIdx.x, t = threadIdx.x;
  const size_t base = (size_t)row * K;
  float v[8];
  float ss = 0.f;
  #pragma unroll
  for (int j = 0; j < 2; j++) {
    float4 lv = *(const float4*)(x + base + j * 1024 + t * 4);
    v[j*4+0] = lv.x; v[j*4+1] = lv.y; v[j*4+2] = lv.z; v[j*4+3] = lv.w;
  }
  #pragma unroll
  for (int i = 0; i < 8; i++) ss += v[i] * v[i];
  ss = block_sum_f(ss);
  const float r = 1.0f / sqrtf(ss / (float)K + 1e-5f);
  float amax = 0.f;
  #pragma unroll
  for (int i = 0; i < 8; i++) { v[i] *= r; amax = fmaxf(amax, fabsf(v[i])); }
  amax = block_max_f(amax);
  amax = fmaxf(amax, 1e-5f);
  const float scale = 127.0f / amax;
  #pragma unroll
  for (int j = 0; j < 2; j++) {
    float q[4];
    #pragma unroll
    for (int e = 0; e < 4; e++)
      q[e] = fminf(fmaxf(rintf(v[j*4+e] * scale), -128.f), 127.f);
    *(unsigned*)(xq + base + j * 1024 + t * 4) = pack4i(q[0], q[1], q[2], q[3]);
  }
  if (t == 0) fx[row] = amax / 127.0f;
}

// ---------- LayerNorm -> rms_norm -> act_quant: bf16 h rows -> int8 hq (N = 8192) ----
__global__ __launch_bounds__(256) void ln_rms_quant(const bf16_t* __restrict__ h,
                                                    char* __restrict__ hq,
                                                    const float* __restrict__ g,
                                                    const float* __restrict__ bb,
                                                    float* __restrict__ fh, int N) {
  const int row = blockIdx.x, t = threadIdx.x;
  const size_t base = (size_t)row * N;
  float v[32];
  float s = 0.f, ss = 0.f;
  #pragma unroll
  for (int j = 0; j < 8; j++) {
    const int col = j * 1024 + t * 4;
    bf16x4 q = *(const bf16x4*)(h + base + col);
    v[j*4+0] = (float)q[0]; v[j*4+1] = (float)q[1];
    v[j*4+2] = (float)q[2]; v[j*4+3] = (float)q[3];
  }
  #pragma unroll
  for (int i = 0; i < 32; i++) { s += v[i]; ss += v[i] * v[i]; }
  s = block_sum_f(s);
  ss = block_sum_f(ss);
  const float mu = s / (float)N;
  const float var = ss / (float)N - mu * mu;
  const float rstd = 1.0f / sqrtf(var + 1e-5f);
  float ss2 = 0.f;
  #pragma unroll
  for (int j = 0; j < 8; j++) {
    const int col = j * 1024 + t * 4;
    float4 gv = *(const float4*)(g + col);
    float4 bv = *(const float4*)(bb + col);
    float y0 = (v[j*4+0] - mu) * rstd * gv.x + bv.x;
    float y1 = (v[j*4+1] - mu) * rstd * gv.y + bv.y;
    float y2 = (v[j*4+2] - mu) * rstd * gv.z + bv.z;
    float y3 = (v[j*4+3] - mu) * rstd * gv.w + bv.w;
    v[j*4+0] = y0; v[j*4+1] = y1; v[j*4+2] = y2; v[j*4+3] = y3;
    ss2 += y0*y0 + y1*y1 + y2*y2 + y3*y3;
  }
  ss2 = block_sum_f(ss2);
  const float r2 = 1.0f / sqrtf(ss2 / (float)N + 1e-5f);
  float amax = 0.f;
  #pragma unroll
  for (int i = 0; i < 32; i++) { v[i] *= r2; amax = fmaxf(amax, fabsf(v[i])); }
  amax = block_max_f(amax);
  amax = fmaxf(amax, 1e-5f);
  const float scale = 127.0f / amax;
  #pragma unroll
  for (int j = 0; j < 8; j++) {
    const int col = j * 1024 + t * 4;
    float q[4];
    #pragma unroll
    for (int e = 0; e < 4; e++)
      q[e] = fminf(fmaxf(rintf(v[j*4+e] * scale), -128.f), 127.f);
    *(unsigned*)(hq + base + col) = pack4i(q[0], q[1], q[2], q[3]);
  }
  if (t == 0) fh[row] = amax / 127.0f;
}

// ================= 256x256 i8 GEMM, 4-deep pipeline (B stored [N][K]) =================
// 8 waves (2Mx4N). BK=64 -> one mfma_i32_16x16x64_i8 per frag pair.
// LDS: FOUR 32KB buffers (A 16KB + B 16KB each) = 128 KiB. Subtile = 1KB
// [16 rows][4 x 16B slots], phys_slot = slot ^ ((row>>1)&3) (conflict-free b128).
// Per tile t: stage t+3 into buf (cur+3)&3 FIRST (its last reader was tile t-1,
// separated by a barrier), then 12 ds_read_b128 + 32 MFMA (compiler-counted lgkm),
// then counted guard vmcnt(8/4/0) ensuring t+1 landed, then ONE barrier.
// t+1's loads thus get ~3 tile-computes of in-flight time.
template<int EPI, bool STORE_BF16>
__global__ __launch_bounds__(512, 2) void gemm256(const char* __restrict__ A,
                                                  const char* __restrict__ B,
                                                  const float* __restrict__ rowf,
                                                  const float* __restrict__ wf,
                                                  const float* __restrict__ bias,
                                                  float* __restrict__ Cf,
                                                  bf16_t* __restrict__ Cb,
                                                  int M, int N, int K) {
  __shared__ char smem[131072];   // 4 buffers x (A 16KB | B 16KB)

  const int ntile = N >> 8;
  const int cpx = gridDim.x >> 3;                 // blocks per XCD (grids % 8 == 0)
  const int bid = blockIdx.x;
  const int xcd = bid & 7, local = bid >> 3;
  // L2-aware order within XCD: bm varies fastest so a concurrent round shares
  // A-panels AND B-panels (mrows = 4 for both our GEMM shapes).
  int wg;
  const int mrows = cpx / ntile;
  if (mrows * ntile == cpx && mrows > 0) {
    const int bm_l = local % mrows, bn_i = local / mrows;
    wg = (xcd * mrows + bm_l) * ntile + bn_i;
  } else {
    wg = xcd * cpx + local;
  }
  const int bm = wg / ntile, bn = wg % ntile;
  const int tm = bm << 8, tn = bn << 8;

  const int tid = threadIdx.x;
  const int w = tid >> 6, lane = tid & 63;
  const int wm = w >> 2, wn = w & 3;              // 2 x 4 wave grid
  const int ln15 = lane & 15;

  // ---- staging: wave w stages rowblk w (lo) and 8+w (hi) of each operand.
  const int srcRow = lane >> 2;
  const int srcCol = (((lane & 3) ^ ((lane >> 3) & 3)) << 4);
  const size_t KS = (size_t)K;
  const char* pAb = A + (size_t)(tm + w * 16 + srcRow) * KS + srcCol;
  const char* pBb = B + (size_t)(tn + w * 16 + srcRow) * KS + srcCol;
  const size_t hiO = (size_t)128 * KS;            // +128 rows for the hi half
  const int dA = w * 1024;                        // byte offset of wave's subtile

  // ---- fragment read offset: row=ln15, global slot g=lane>>4,
  // phys slot = g ^ ((ln15>>1)&3); 16B aligned.
  const int foff = ln15 * 64 + ((((lane >> 4) ^ ((ln15 >> 1) & 3))) << 4);

  i32x4 acc[8][4] = {};
  const int NT = K >> 6;

#define SB __builtin_amdgcn_sched_barrier(0)
#define BAR { SB; __builtin_amdgcn_s_barrier(); SB; }
#define ST_ALL(bb, kt) { const size_t ko = (size_t)(kt) * 64;              \
    gl_lds16(pAb + ko,       smem + ((bb) << 15) + dA);                    \
    gl_lds16(pAb + hiO + ko, smem + ((bb) << 15) + 8192 + dA);             \
    gl_lds16(pBb + ko,       smem + ((bb) << 15) + 16384 + dA);            \
    gl_lds16(pBb + hiO + ko, smem + ((bb) << 15) + 16384 + 8192 + dA); }
#define MM(AF, BF, MB, NB)                                                   \
  _Pragma("unroll") for (int m4 = 0; m4 < 4; m4++)                           \
    _Pragma("unroll") for (int n2 = 0; n2 < 2; n2++)                         \
      acc[(MB)+m4][(NB)+n2] = __builtin_amdgcn_mfma_i32_16x16x64_i8(         \
          AF[m4], BF[n2], acc[(MB)+m4][(NB)+n2], 0, 0, 0);

  // ---- prologue: stage tiles 0,1,2 into buffers 0,1,2; wait tile 0 ----
  ST_ALL(0, 0); ST_ALL(1, 1); ST_ALL(2, 2);
  asm volatile("s_waitcnt vmcnt(8)" ::: "memory");
  BAR;

  int cur = 0;
  for (int t = 0; t < NT; ++t) {
    const int cb = cur << 15;
    const int stg = (cur + 3) & 3;
    if (t + 3 < NT) ST_ALL(stg, t + 3);     // stage early: 3 tiles of latency cover
    SB;
    const char* sA = smem + cb;
    const char* sB = smem + cb + 16384;
    i32x4 afL[4], afH[4], bL[2], bH[2];
    #pragma unroll
    for (int m4 = 0; m4 < 4; m4++)
      afL[m4] = *(const i32x4*)(sA + (wm * 4 + m4) * 1024 + foff);
    #pragma unroll
    for (int n2 = 0; n2 < 2; n2++)
      bL[n2] = *(const i32x4*)(sB + (wn * 2 + n2) * 1024 + foff);
    #pragma unroll
    for (int m4 = 0; m4 < 4; m4++)
      afH[m4] = *(const i32x4*)(sA + 8192 + (wm * 4 + m4) * 1024 + foff);
    #pragma unroll
    for (int n2 = 0; n2 < 2; n2++)
      bH[n2] = *(const i32x4*)(sB + 8192 + (wn * 2 + n2) * 1024 + foff);
    __builtin_amdgcn_s_setprio(1);
    MM(afL, bL, 0, 0);
    MM(afH, bL, 4, 0);
    MM(afH, bH, 4, 2);
    MM(afL, bH, 0, 2);
    __builtin_amdgcn_s_setprio(0);
    if (t + 1 < NT) {                        // counted guard: t+1 fully landed
      if (t + 3 < NT)      asm volatile("s_waitcnt vmcnt(8)" ::: "memory");
      else if (t + 2 < NT) asm volatile("s_waitcnt vmcnt(4)" ::: "memory");
      else                 asm volatile("s_waitcnt vmcnt(0)" ::: "memory");
      BAR;                                   // one barrier per tile
    }
    cur = (cur + 1) & 3;
  }
#undef ST_ALL
#undef MM

  // ---- epilogue: dequant + bias (+ SiLU+GELU) ----
  const float fwv = wf[0];
  const int rq = (lane >> 4) << 2;
  float rsc[8][4];
  #pragma unroll
  for (int m = 0; m < 8; m++)
    #pragma unroll
    for (int r = 0; r < 4; r++)
      rsc[m][r] = rowf[tm + (m >> 2) * 128 + wm * 64 + (m & 3) * 16 + rq + r] * fwv;

  #pragma unroll
  for (int m = 0; m < 8; m++) {
    #pragma unroll
    for (int n = 0; n < 4; n++) {
      const int col = tn + (n >> 1) * 128 + wn * 32 + (n & 1) * 16 + ln15;
      const float bv = bias[col];
      #pragma unroll
      for (int r = 0; r < 4; r++) {
        const int row = tm + (m >> 2) * 128 + wm * 64 + (m & 3) * 16 + rq + r;
        float val = (float)acc[m][n][r] * rsc[m][r] + bv;
        if (EPI == 1) {
          float sl = val / (1.0f + expf(-val));                       // SiLU
          val = 0.5f * sl * (1.0f + erff(sl * 0.70710678118654752f)); // exact GELU
        }
        if (STORE_BF16) Cb[(size_t)row * N + col] = (bf16_t)val;
        else            Cf[(size_t)row * N + col] = val;
      }
    }
  }
}

extern "C" void kernel_launch(void* const* d_in, const int* in_sizes, int n_in,
                              void* d_out, int out_size, void* d_ws, size_t ws_size,
                              hipStream_t stream) {
  const float* x   = (const float*)d_in[0];
  const float* w1  = (const float*)d_in[1];
  const float* b1  = (const float*)d_in[2];
  const float* lng = (const float*)d_in[3];
  const float* lnb = (const float*)d_in[4];
  const float* w2  = (const float*)d_in[5];
  const float* b2  = (const float*)d_in[6];
  float* out = (float*)d_out;

  const int inner = in_sizes[2];           // 8192
  const int d     = in_sizes[1] / inner;   // 2048
  const int M     = in_sizes[0] / d;       // 8192

  char* ws = (char*)d_ws;
  size_t off = 0;
  double* part = (double*)(ws + off); off += 1024 * 8;
  float*  fw   = (float*)(ws + off);  off += 256;
  float*  fx   = (float*)(ws + off);  off += (size_t)M * 4;
  float*  fh   = (float*)(ws + off);  off += (size_t)M * 4;
  char*   w1q  = ws + off;            off += (size_t)inner * d;
  char*   w2q  = ws + off;            off += (size_t)inner * d;

  // chunk: xq (MC*d i8) + h (MC*inner bf16) + hq (MC*inner i8)
  int MC = M;  // multiple of 256
  while (MC > 256 && off + (size_t)MC * ((size_t)d + 3 * (size_t)inner) > ws_size) MC >>= 1;
  char*   xq = ws + off;              off += (size_t)MC * d;
  bf16_t* h  = (bf16_t*)(ws + off);   off += (size_t)MC * inner * 2;
  char*   hq = ws + off;

  const int nw = inner * d;
  const int n4 = nw / 4;

  wabs_partial<<<1024, 256, 0, stream>>>(w1, n4, part);
  wabs_final<<<1, 256, 0, stream>>>(part, 1024, (double)nw, fw + 0);
  wabs_partial<<<1024, 256, 0, stream>>>(w2, n4, part);
  wabs_final<<<1, 256, 0, stream>>>(part, 1024, (double)nw, fw + 1);
  quant_w<<<n4 / 256, 256, 0, stream>>>(w1, fw + 0, w1q, n4);
  quant_w<<<n4 / 256, 256, 0, stream>>>(w2, fw + 1, w2q, n4);

  for (int mc = 0; mc < M; mc += MC) {
    rms_quant_x<<<MC, 256, 0, stream>>>(x + (size_t)mc * d, xq, fx, d);

    const int g1 = (MC / 256) * (inner / 256);
    gemm256<1, true><<<g1, 512, 0, stream>>>(xq, w1q, fx, fw + 0, b1,
                                             nullptr, h, MC, inner, d);

    ln_rms_quant<<<MC, 256, 0, stream>>>(h, hq, lng, lnb, fh, inner);

    const int g2 = (MC / 256) * (d / 256);
    gemm256<0, false><<<g2, 512, 0, stream>>>(hq, w2q, fh, fw + 1, b2,
                                              out + (size_t)mc * d, nullptr, MC, d, inner);
  }
}

// Round 8
// 433.711 us; speedup vs baseline: 1.6784x; 1.0791x over previous
//
#include <hip/hip_runtime.h>
#include <hip/hip_bf16.h>
#include <math.h>

typedef __bf16 bf16_t;
typedef __bf16 bf16x4 __attribute__((ext_vector_type(4)));
typedef int i32x4 __attribute__((ext_vector_type(4)));

#define AS1 __attribute__((address_space(1)))
#define AS3 __attribute__((address_space(3)))

__device__ __forceinline__ void gl_lds16(const char* g, char* l) {
  __builtin_amdgcn_global_load_lds((const AS1 void*)g, (AS3 void*)l, 16, 0, 0);
}

__device__ __forceinline__ unsigned pack4i(float a, float b, float c, float d) {
  return ((unsigned)(unsigned char)(int)a) | ((unsigned)(unsigned char)(int)b << 8) |
         ((unsigned)(unsigned char)(int)c << 16) | ((unsigned)(unsigned char)(int)d << 24);
}

// ---------- block reductions (256 threads = 4 waves) ----------
__device__ __forceinline__ float block_sum_f(float v) {
  __shared__ float sb[4];
  #pragma unroll
  for (int o = 32; o; o >>= 1) v += __shfl_xor(v, o);
  if ((threadIdx.x & 63) == 0) sb[threadIdx.x >> 6] = v;
  __syncthreads();
  v = sb[0] + sb[1] + sb[2] + sb[3];
  __syncthreads();
  return v;
}
__device__ __forceinline__ float block_max_f(float v) {
  __shared__ float sm[4];
  #pragma unroll
  for (int o = 32; o; o >>= 1) v = fmaxf(v, __shfl_xor(v, o));
  if ((threadIdx.x & 63) == 0) sm[threadIdx.x >> 6] = v;
  __syncthreads();
  v = fmaxf(fmaxf(sm[0], sm[1]), fmaxf(sm[2], sm[3]));
  __syncthreads();
  return v;
}

// ---------- weight absmean (f64 accumulation, two-pass, deterministic) ----------
__global__ __launch_bounds__(256) void wabs_partial(const float* __restrict__ w, int n4,
                                                    double* __restrict__ part) {
  const float4* w4 = (const float4*)w;
  double s = 0.0;
  const int stride = gridDim.x * blockDim.x;
  for (int i = blockIdx.x * blockDim.x + threadIdx.x; i < n4; i += stride) {
    float4 v = w4[i];
    s += (double)fabsf(v.x) + (double)fabsf(v.y) + (double)fabsf(v.z) + (double)fabsf(v.w);
  }
  #pragma unroll
  for (int o = 32; o; o >>= 1) s += __shfl_xor(s, o);
  __shared__ double sd[4];
  if ((threadIdx.x & 63) == 0) sd[threadIdx.x >> 6] = s;
  __syncthreads();
  if (threadIdx.x == 0) part[blockIdx.x] = sd[0] + sd[1] + sd[2] + sd[3];
}

__global__ __launch_bounds__(256) void wabs_final(const double* __restrict__ part, int np,
                                                  double n, float* __restrict__ fwout) {
  double s = 0.0;
  for (int i = threadIdx.x; i < np; i += blockDim.x) s += part[i];
  #pragma unroll
  for (int o = 32; o; o >>= 1) s += __shfl_xor(s, o);
  __shared__ double sd[4];
  if ((threadIdx.x & 63) == 0) sd[threadIdx.x >> 6] = s;
  __syncthreads();
  if (threadIdx.x == 0) {
    double mean = (sd[0] + sd[1] + sd[2] + sd[3]) / n;
    fwout[0] = (float)fmax(mean, 1e-5);
  }
}

// ---------- ternary weight quantization -> int8 {-1,0,1} ----------
__global__ __launch_bounds__(256) void quant_w(const float* __restrict__ w,
                                               const float* __restrict__ fw,
                                               char* __restrict__ wq, int n4) {
  int i = blockIdx.x * blockDim.x + threadIdx.x;
  if (i >= n4) return;
  const float s = 1.0f / fw[0];
  float4 v = ((const float4*)w)[i];
  ((unsigned*)wq)[i] = pack4i(fminf(fmaxf(rintf(v.x * s), -1.f), 1.f),
                              fminf(fmaxf(rintf(v.y * s), -1.f), 1.f),
                              fminf(fmaxf(rintf(v.z * s), -1.f), 1.f),
                              fminf(fmaxf(rintf(v.w * s), -1.f), 1.f));
}

// ---------- rms_norm + act_quant of x rows (K = 2048) -> int8 + scale ----------
__global__ __launch_bounds__(256) void rms_quant_x(const float* __restrict__ x,
                                                   char* __restrict__ xq,
                                                   float* __restrict__ fx, int K) {
  const int row = blockIdx.x, t = threadIdx.x;
  const size_t base = (size_t)row * K;
  float v[8];
  float ss = 0.f;
  #pragma unroll
  for (int j = 0; j < 2; j++) {
    float4 lv = *(const float4*)(x + base + j * 1024 + t * 4);
    v[j*4+0] = lv.x; v[j*4+1] = lv.y; v[j*4+2] = lv.z; v[j*4+3] = lv.w;
  }
  #pragma unroll
  for (int i = 0; i < 8; i++) ss += v[i] * v[i];
  ss = block_sum_f(ss);
  const float r = 1.0f / sqrtf(ss / (float)K + 1e-5f);
  float amax = 0.f;
  #pragma unroll
  for (int i = 0; i < 8; i++) { v[i] *= r; amax = fmaxf(amax, fabsf(v[i])); }
  amax = block_max_f(amax);
  amax = fmaxf(amax, 1e-5f);
  const float scale = 127.0f / amax;
  #pragma unroll
  for (int j = 0; j < 2; j++) {
    float q[4];
    #pragma unroll
    for (int e = 0; e < 4; e++)
      q[e] = fminf(fmaxf(rintf(v[j*4+e] * scale), -128.f), 127.f);
    *(unsigned*)(xq + base + j * 1024 + t * 4) = pack4i(q[0], q[1], q[2], q[3]);
  }
  if (t == 0) fx[row] = amax / 127.0f;
}

// ---------- LayerNorm -> rms_norm -> act_quant: bf16 h rows -> int8 hq (N = 8192) ----
__global__ __launch_bounds__(256) void ln_rms_quant(const bf16_t* __restrict__ h,
                                                    char* __restrict__ hq,
                                                    const float* __restrict__ g,
                                                    const float* __restrict__ bb,
                                                    float* __restrict__ fh, int N) {
  const int row = blockIdx.x, t = threadIdx.x;
  const size_t base = (size_t)row * N;
  float v[32];
  float s = 0.f, ss = 0.f;
  #pragma unroll
  for (int j = 0; j < 8; j++) {
    const int col = j * 1024 + t * 4;
    bf16x4 q = *(const bf16x4*)(h + base + col);
    v[j*4+0] = (float)q[0]; v[j*4+1] = (float)q[1];
    v[j*4+2] = (float)q[2]; v[j*4+3] = (float)q[3];
  }
  #pragma unroll
  for (int i = 0; i < 32; i++) { s += v[i]; ss += v[i] * v[i]; }
  s = block_sum_f(s);
  ss = block_sum_f(ss);
  const float mu = s / (float)N;
  const float var = ss / (float)N - mu * mu;
  const float rstd = 1.0f / sqrtf(var + 1e-5f);
  float ss2 = 0.f;
  #pragma unroll
  for (int j = 0; j < 8; j++) {
    const int col = j * 1024 + t * 4;
    float4 gv = *(const float4*)(g + col);
    float4 bv = *(const float4*)(bb + col);
    float y0 = (v[j*4+0] - mu) * rstd * gv.x + bv.x;
    float y1 = (v[j*4+1] - mu) * rstd * gv.y + bv.y;
    float y2 = (v[j*4+2] - mu) * rstd * gv.z + bv.z;
    float y3 = (v[j*4+3] - mu) * rstd * gv.w + bv.w;
    v[j*4+0] = y0; v[j*4+1] = y1; v[j*4+2] = y2; v[j*4+3] = y3;
    ss2 += y0*y0 + y1*y1 + y2*y2 + y3*y3;
  }
  ss2 = block_sum_f(ss2);
  const float r2 = 1.0f / sqrtf(ss2 / (float)N + 1e-5f);
  float amax = 0.f;
  #pragma unroll
  for (int i = 0; i < 32; i++) { v[i] *= r2; amax = fmaxf(amax, fabsf(v[i])); }
  amax = block_max_f(amax);
  amax = fmaxf(amax, 1e-5f);
  const float scale = 127.0f / amax;
  #pragma unroll
  for (int j = 0; j < 8; j++) {
    const int col = j * 1024 + t * 4;
    float q[4];
    #pragma unroll
    for (int e = 0; e < 4; e++)
      q[e] = fminf(fmaxf(rintf(v[j*4+e] * scale), -128.f), 127.f);
    *(unsigned*)(hq + base + col) = pack4i(q[0], q[1], q[2], q[3]);
  }
  if (t == 0) fh[row] = amax / 127.0f;
}

// ============ 256x256 i8 GEMM, fine-phase schedule (B stored [N][K]) ============
// 8 waves (2Mx4N), wave out 128x64. BK=128 -> 2 k-instr (mfma_i32_16x16x64_i8).
// LDS: A = [2 buf][2 half][8 rowblk][16 rows][8 x 16B slots] = 64KB at 0; B same
// at 65536. Slot swizzle: phys_slot = slot ^ (row&7) -> every 8-lane group of a
// ds_read_b128 covers all 8 slots (conflict-free). Staged via pre-swizzled global
// source col, linear LDS dest.
// Per K-tile, 4 phases, quadrants (mh,nh) = (0,0),(0,1),(1,1),(1,0):
//   ph0: stage {A-lo,B-lo}(t+1) [4 ld]; vmcnt(8); BAR; read afL(8)+bL(4); 16 MFMA
//   ph1: stage {B-hi}(t+1) [2];         vmcnt(8); BAR; read bH(4);        16 MFMA
//   ph2: stage {A-hi}(t+1) [2];         vmcnt(8); BAR; read afH(8);       16 MFMA
//   ph3: (no stage/guard/barrier)                                         16 MFMA
// Guard invariant: piece staged at (t-1, phase q) has exactly 8 newer loads at
// (t, phase q)'s guard (s={4,2,2,0}: post-stage sum = 8 for q=0,1,2) -> uniform
// vmcnt(8). Tail tile (no stages): vmcnt(4/2/0). WAR: each staged region's last
// ds_read is >=1 barrier before the stage issue. Frag liveness: bL whole tile,
// afL ph0-1, bH ph1-2, afH ph2-3 -> peak ~64 frag VGPR, stays 2 waves/SIMD.
template<int EPI, bool STORE_BF16>
__global__ __launch_bounds__(512, 2) void gemm256(const char* __restrict__ A,
                                                  const char* __restrict__ B,
                                                  const float* __restrict__ rowf,
                                                  const float* __restrict__ wf,
                                                  const float* __restrict__ bias,
                                                  float* __restrict__ Cf,
                                                  bf16_t* __restrict__ Cb,
                                                  int M, int N, int K) {
  __shared__ char smem[131072];

  const int ntile = N >> 8;
  const int cpx = gridDim.x >> 3;                 // blocks per XCD (grid % 8 == 0)
  const int bid = blockIdx.x;
  const int xcd = bid & 7, local = bid >> 3;
  int wg;
  const int mrows = cpx / ntile;                  // L2-aware: bm varies fastest
  if (mrows * ntile == cpx && mrows > 0) {
    const int bm_l = local % mrows, bn_i = local / mrows;
    wg = (xcd * mrows + bm_l) * ntile + bn_i;
  } else {
    wg = xcd * cpx + local;
  }
  const int bm = wg / ntile, bn = wg % ntile;
  const int tm = bm << 8, tn = bn << 8;

  const int tid = threadIdx.x;
  const int w = tid >> 6, lane = tid & 63;
  const int wm = w >> 2, wn = w & 3;
  const int ln15 = lane & 15;

  // staging: wave w owns rowblk w (16 rows x 128B = 2 gl_lds) of each half.
  const int srow = lane >> 3;                                  // 0..7
  const int scol = ((lane & 7) ^ srow) << 4;                   // pre-swizzled slot
  const size_t KS = (size_t)K;
  const char* pAst = A + (size_t)(tm + w * 16 + srow) * KS + scol;
  const char* pBst = B + (size_t)(tn + w * 16 + srow) * KS + scol;
  const size_t hiO = (size_t)128 * KS;                         // +128 rows (hi half)
  const size_t r8 = (size_t)8 * KS;                            // +8 rows (2nd gl_lds)
  const int dW = w * 2048;                                     // wave rowblk offset

  // frag read: row ln15, k-slot (kk*4 + lane>>4), phys = slot ^ (ln15&7)
  int foffk[2];
  #pragma unroll
  for (int kk = 0; kk < 2; kk++)
    foffk[kk] = ln15 * 128 + ((((kk << 2) + (lane >> 4)) ^ (ln15 & 7)) << 4);

  i32x4 acc[8][4] = {};
  const int NT = K >> 7;                                       // K-tiles of 128

#define SB __builtin_amdgcn_sched_barrier(0)
#define BAR { SB; __builtin_amdgcn_s_barrier(); SB; }
#define ST_A(bb, hh, kt) { const char* p = pAst + ((hh) ? hiO : 0) + (size_t)(kt) * 128; \
    char* dst = smem + (bb) * 32768 + (hh) * 16384 + dW;                                 \
    gl_lds16(p, dst); gl_lds16(p + r8, dst + 1024); }
#define ST_B(bb, hh, kt) { const char* p = pBst + ((hh) ? hiO : 0) + (size_t)(kt) * 128; \
    char* dst = smem + 65536 + (bb) * 32768 + (hh) * 16384 + dW;                         \
    gl_lds16(p, dst); gl_lds16(p + r8, dst + 1024); }
#define MM(AF, BF, MB, NB)                                                   \
  _Pragma("unroll") for (int kk = 0; kk < 2; kk++)                           \
    _Pragma("unroll") for (int m4 = 0; m4 < 4; m4++)                         \
      _Pragma("unroll") for (int n2 = 0; n2 < 2; n2++)                       \
        acc[(MB)+m4][(NB)+n2] = __builtin_amdgcn_mfma_i32_16x16x64_i8(       \
            AF[m4][kk], BF[n2][kk], acc[(MB)+m4][(NB)+n2], 0, 0, 0);
#define VM(n) asm volatile("s_waitcnt vmcnt(" #n ")" ::: "memory")

  // prologue: stage tile0 in guard order {Alo,Blo},{Bhi},{Ahi} (8 loads)
  ST_A(0, 0, 0); ST_B(0, 0, 0); ST_B(0, 1, 0); ST_A(0, 1, 0);

  for (int t = 0; t < NT; ++t) {
    const int b = t & 1, nb = b ^ 1;
    const char* sA = smem + b * 32768;
    const char* sB = smem + 65536 + b * 32768;
    i32x4 afL[4][2], afH[4][2], bL[2][2], bH[2][2];
    // ---- ph0: quadrant (0,0)
    if (t + 1 < NT) { ST_A(nb, 0, t + 1); ST_B(nb, 0, t + 1); VM(8); }
    else            { VM(4); }
    BAR;
    #pragma unroll
    for (int m4 = 0; m4 < 4; m4++)
      #pragma unroll
      for (int kk = 0; kk < 2; kk++)
        afL[m4][kk] = *(const i32x4*)(sA + (wm * 4 + m4) * 2048 + foffk[kk]);
    #pragma unroll
    for (int n2 = 0; n2 < 2; n2++)
      #pragma unroll
      for (int kk = 0; kk < 2; kk++)
        bL[n2][kk] = *(const i32x4*)(sB + (wn * 2 + n2) * 2048 + foffk[kk]);
    __builtin_amdgcn_s_setprio(1);
    MM(afL, bL, 0, 0);
    __builtin_amdgcn_s_setprio(0);
    // ---- ph1: quadrant (0,1) — needs B-hi
    if (t + 1 < NT) { ST_B(nb, 1, t + 1); VM(8); }
    else            { VM(2); }
    BAR;
    #pragma unroll
    for (int n2 = 0; n2 < 2; n2++)
      #pragma unroll
      for (int kk = 0; kk < 2; kk++)
        bH[n2][kk] = *(const i32x4*)(sB + 16384 + (wn * 2 + n2) * 2048 + foffk[kk]);
    __builtin_amdgcn_s_setprio(1);
    MM(afL, bH, 0, 2);
    __builtin_amdgcn_s_setprio(0);
    // ---- ph2: quadrant (1,1) — needs A-hi
    if (t + 1 < NT) { ST_A(nb, 1, t + 1); VM(8); }
    else            { VM(0); }
    BAR;
    #pragma unroll
    for (int m4 = 0; m4 < 4; m4++)
      #pragma unroll
      for (int kk = 0; kk < 2; kk++)
        afH[m4][kk] = *(const i32x4*)(sA + 16384 + (wm * 4 + m4) * 2048 + foffk[kk]);
    __builtin_amdgcn_s_setprio(1);
    MM(afH, bH, 4, 2);
    __builtin_amdgcn_s_setprio(0);
    // ---- ph3: quadrant (1,0) — registers only
    __builtin_amdgcn_s_setprio(1);
    MM(afH, bL, 4, 0);
    __builtin_amdgcn_s_setprio(0);
  }
#undef ST_A
#undef ST_B
#undef MM
#undef VM

  // ---- epilogue: dequant + bias (+ SiLU+GELU) ----
  const float fwv = wf[0];
  const int rq = (lane >> 4) << 2;
  float rsc[8][4];
  #pragma unroll
  for (int m = 0; m < 8; m++)
    #pragma unroll
    for (int r = 0; r < 4; r++)
      rsc[m][r] = rowf[tm + (m >> 2) * 128 + wm * 64 + (m & 3) * 16 + rq + r] * fwv;

  #pragma unroll
  for (int m = 0; m < 8; m++) {
    #pragma unroll
    for (int n = 0; n < 4; n++) {
      const int col = tn + (n >> 1) * 128 + wn * 32 + (n & 1) * 16 + ln15;
      const float bv = bias[col];
      #pragma unroll
      for (int r = 0; r < 4; r++) {
        const int row = tm + (m >> 2) * 128 + wm * 64 + (m & 3) * 16 + rq + r;
        float val = (float)acc[m][n][r] * rsc[m][r] + bv;
        if (EPI == 1) {
          float sl = val / (1.0f + __expf(-val));                     // SiLU
          val = 0.5f * sl * (1.0f + erff(sl * 0.70710678118654752f)); // exact GELU
        }
        if (STORE_BF16) Cb[(size_t)row * N + col] = (bf16_t)val;
        else            Cf[(size_t)row * N + col] = val;
      }
    }
  }
}

extern "C" void kernel_launch(void* const* d_in, const int* in_sizes, int n_in,
                              void* d_out, int out_size, void* d_ws, size_t ws_size,
                              hipStream_t stream) {
  const float* x   = (const float*)d_in[0];
  const float* w1  = (const float*)d_in[1];
  const float* b1  = (const float*)d_in[2];
  const float* lng = (const float*)d_in[3];
  const float* lnb = (const float*)d_in[4];
  const float* w2  = (const float*)d_in[5];
  const float* b2  = (const float*)d_in[6];
  float* out = (float*)d_out;

  const int inner = in_sizes[2];           // 8192
  const int d     = in_sizes[1] / inner;   // 2048
  const int M     = in_sizes[0] / d;       // 8192

  char* ws = (char*)d_ws;
  size_t off = 0;
  double* part = (double*)(ws + off); off += 1024 * 8;
  float*  fw   = (float*)(ws + off);  off += 256;
  float*  fx   = (float*)(ws + off);  off += (size_t)M * 4;
  float*  fh   = (float*)(ws + off);  off += (size_t)M * 4;
  char*   w1q  = ws + off;            off += (size_t)inner * d;
  char*   w2q  = ws + off;            off += (size_t)inner * d;

  // chunk: xq (MC*d i8) + h (MC*inner bf16) + hq (MC*inner i8)
  int MC = M;  // multiple of 256
  while (MC > 256 && off + (size_t)MC * ((size_t)d + 3 * (size_t)inner) > ws_size) MC >>= 1;
  char*   xq = ws + off;              off += (size_t)MC * d;
  bf16_t* h  = (bf16_t*)(ws + off);   off += (size_t)MC * inner * 2;
  char*   hq = ws + off;

  const int nw = inner * d;
  const int n4 = nw / 4;

  wabs_partial<<<1024, 256, 0, stream>>>(w1, n4, part);
  wabs_final<<<1, 256, 0, stream>>>(part, 1024, (double)nw, fw + 0);
  wabs_partial<<<1024, 256, 0, stream>>>(w2, n4, part);
  wabs_final<<<1, 256, 0, stream>>>(part, 1024, (double)nw, fw + 1);
  quant_w<<<n4 / 256, 256, 0, stream>>>(w1, fw + 0, w1q, n4);
  quant_w<<<n4 / 256, 256, 0, stream>>>(w2, fw + 1, w2q, n4);

  for (int mc = 0; mc < M; mc += MC) {
    rms_quant_x<<<MC, 256, 0, stream>>>(x + (size_t)mc * d, xq, fx, d);

    const int g1 = (MC / 256) * (inner / 256);
    gemm256<1, true><<<g1, 512, 0, stream>>>(xq, w1q, fx, fw + 0, b1,
                                             nullptr, h, MC, inner, d);

    ln_rms_quant<<<MC, 256, 0, stream>>>(h, hq, lng, lnb, fh, inner);

    const int g2 = (MC / 256) * (d / 256);
    gemm256<0, false><<<g2, 512, 0, stream>>>(hq, w2q, fh, fw + 1, b2,
                                              out + (size_t)mc * d, nullptr, MC, d, inner);
  }
}